// Round 2
// baseline (516.222 us; speedup 1.0000x reference)
//
#include <hip/hip_runtime.h>
#include <math.h>

// Problem constants (match reference)
#define BH 128
#define S  8192
#define D  64
#define ALPHA_F 0.999f

// Tiling
#define CHUNK   512
#define NCHUNK  (S / CHUNK)   // 16
#define PSTRIDE 72            // floats per partial record: [0]=m, [1]=z, [4..67]=o[64]

// Kernel 1: per-(bh, chunk) partial exp-weighted attention, single-pass
// online-softmax streaming. 256 threads = 16 groups x 16 lanes. Each group
// of 16 lanes processes one s-row per iteration: k dot (float4/lane +
// shfl_xor reduce), online max/rescale, v accumulate. No LDS in the main
// loop, no barriers; k and v loads interleaved for latency hiding.
__global__ __launch_bounds__(256) void partial_kernel(
    const float* __restrict__ q,     // [BH,1,D]
    const float* __restrict__ k,     // [BH,S,D]
    const float* __restrict__ v,     // [BH,S,D]
    const float* __restrict__ mask,  // [BH,1,S]
    float* __restrict__ ws)
{
    const int blk   = blockIdx.x;
    const int bh    = blk / NCHUNK;
    const int chunk = blk % NCHUNK;
    const int s0    = chunk * CHUNK;
    const int t     = threadIdx.x;
    const int lid   = t & 15;   // lane within 16-lane group
    const int g     = t >> 4;   // group 0..15

    __shared__ float gm[16];
    __shared__ float gz[16];
    __shared__ float go[16][64];

    // q fragment for this lane (reused across all s)
    const float4 q4 = *reinterpret_cast<const float4*>(q + bh * D + lid * 4);

    const float* kb = k + (size_t)bh * S * D;
    const float* vb = v + (size_t)bh * S * D;
    const float* mb = mask + (size_t)bh * S;

    float  m  = -INFINITY;
    float  z  = 0.f;
    float4 o4 = {0.f, 0.f, 0.f, 0.f};

    #pragma unroll 4
    for (int it = 0; it < CHUNK / 16; ++it) {
        const int sl = it * 16 + g;
        const int s  = s0 + sl;
        const float4 k4 = *reinterpret_cast<const float4*>(kb + (size_t)s * D + lid * 4);
        const float4 v4 = *reinterpret_cast<const float4*>(vb + (size_t)s * D + lid * 4);

        float d = q4.x * k4.x + q4.y * k4.y + q4.z * k4.z + q4.w * k4.w;
        d += __shfl_xor(d, 1);
        d += __shfl_xor(d, 2);
        d += __shfl_xor(d, 4);
        d += __shfl_xor(d, 8);
        d += mb[s];                       // mask folded into score (M-invariant)

        const float mn = fmaxf(m, d);
        const float c  = __expf(m - mn);  // == 1.0 exactly when max unchanged
        const float p  = __expf(d - mn);
        z    = z * c + p;
        o4.x = o4.x * c + p * v4.x;
        o4.y = o4.y * c + p * v4.y;
        o4.z = o4.z * c + p * v4.z;
        o4.w = o4.w * c + p * v4.w;
        m    = mn;
    }

    // ---- combine 16 groups within the block ----
    go[g][lid * 4 + 0] = o4.x;
    go[g][lid * 4 + 1] = o4.y;
    go[g][lid * 4 + 2] = o4.z;
    go[g][lid * 4 + 3] = o4.w;
    if (lid == 0) { gm[g] = m; gz[g] = z; }
    __syncthreads();

    if (t < 64) {
        float M = -INFINITY;
        #pragma unroll
        for (int c2 = 0; c2 < 16; ++c2) M = fmaxf(M, gm[c2]);
        float zz = 0.f, oo = 0.f;
        #pragma unroll
        for (int c2 = 0; c2 < 16; ++c2) {
            const float w = __expf(gm[c2] - M);
            zz += w * gz[c2];
            oo += w * go[c2][t];
        }
        float* rec = ws + (size_t)blk * PSTRIDE;
        rec[4 + t] = oo;
        if (t == 0) { rec[0] = M; rec[1] = zz; }
    }
}

// Kernel 2: combine the NCHUNK partials per bh, apply push step, write output.
__global__ __launch_bounds__(64) void reduce_kernel(
    const float* __restrict__ q_push,  // [BH,1,D]
    const float* __restrict__ k_push,  // [BH,1,D]
    const float* __restrict__ v_push,  // [BH,1,D]
    const float* __restrict__ ws,
    float* __restrict__ out)           // [BH,1,D]
{
    const int bh = blockIdx.x;
    const int t  = threadIdx.x;  // 0..63 == d
    const float* base = ws + (size_t)bh * NCHUNK * PSTRIDE;

    float M = -INFINITY;
    #pragma unroll
    for (int c = 0; c < NCHUNK; ++c) M = fmaxf(M, base[c * PSTRIDE]);

    float z = 0.f, o = 0.f;
    #pragma unroll
    for (int c = 0; c < NCHUNK; ++c) {
        const float w = __expf(base[c * PSTRIDE] - M);
        z += w * base[c * PSTRIDE + 1];
        o += w * base[c * PSTRIDE + 4 + t];
    }

    // push-step dot(q_push, k_push) across the 64 lanes
    float pd = q_push[bh * D + t] * k_push[bh * D + t];
    #pragma unroll
    for (int off = 1; off < 64; off <<= 1) pd += __shfl_xor(pd, off);
    const float p = __expf(pd - M);

    // out = (alpha*QKV_exp + p*v_push) / (alpha*Z + p)
    out[bh * D + t] = (ALPHA_F * o + p * v_push[bh * D + t]) / (ALPHA_F * z + p);
}

extern "C" void kernel_launch(void* const* d_in, const int* in_sizes, int n_in,
                              void* d_out, int out_size, void* d_ws, size_t ws_size,
                              hipStream_t stream) {
    const float* q      = (const float*)d_in[0];
    const float* k      = (const float*)d_in[1];
    const float* v      = (const float*)d_in[2];
    const float* q_push = (const float*)d_in[3];
    const float* k_push = (const float*)d_in[4];
    const float* v_push = (const float*)d_in[5];
    const float* mask   = (const float*)d_in[6];
    float* ws  = (float*)d_ws;
    float* out = (float*)d_out;

    partial_kernel<<<dim3(BH * NCHUNK), dim3(256), 0, stream>>>(q, k, v, mask, ws);
    reduce_kernel<<<dim3(BH), dim3(64), 0, stream>>>(q_push, k_push, v_push, ws, out);
}